// Round 1
// 814.050 us; speedup vs baseline: 1.0181x; 1.0181x over previous
//
#include <hip/hip_runtime.h>
#include <hip/hip_bf16.h>
#include <math.h>

// Problem constants (fixed by setup_inputs)
#define B_ 2
#define N_ 4096
#define D_ 2048
#define H_ 16
#define DH_ 128
#define CHUNK_ 256
#define NC_ 16
#define M_ (B_*N_)          // 8192 tokens
#define F3D (3*D_)          // 6144

typedef __bf16 v8bf __attribute__((ext_vector_type(8)));
typedef float  v4f  __attribute__((ext_vector_type(4)));
typedef unsigned short u16x8 __attribute__((ext_vector_type(8)));

__device__ __forceinline__ float bf2f(unsigned short u) {
    union { unsigned int i; float f; } c; c.i = ((unsigned int)u) << 16; return c.f;
}
__device__ __forceinline__ unsigned short f2bf(float f) {
    __hip_bfloat16 h = __float2bfloat16(f);
    return *(unsigned short*)&h;
}

__device__ __forceinline__ void async_copy16(void* lds, const void* g) {
    __builtin_amdgcn_global_load_lds(
        (const __attribute__((address_space(1))) unsigned int*)g,
        (__attribute__((address_space(3))) unsigned int*)lds,
        16, 0, 0);
}

// ---------------- RMSNorm: x (f32) -> xn (bf16), 8 elems/thread ----------------
__global__ __launch_bounds__(256) void k_rmsnorm(const float* __restrict__ x,
                                                 const float* __restrict__ scale,
                                                 __hip_bfloat16* __restrict__ xn)
{
    __shared__ float red[4];
    const int row = blockIdx.x;
    const float4* x4 = (const float4*)(x + (size_t)row * D_);
    float4 a = x4[threadIdx.x*2];
    float4 b = x4[threadIdx.x*2 + 1];
    float ss = a.x*a.x + a.y*a.y + a.z*a.z + a.w*a.w
             + b.x*b.x + b.y*b.y + b.z*b.z + b.w*b.w;
    #pragma unroll
    for (int off = 32; off > 0; off >>= 1) ss += __shfl_down(ss, off, 64);
    if ((threadIdx.x & 63) == 0) red[threadIdx.x >> 6] = ss;
    __syncthreads();
    float tot = red[0] + red[1] + red[2] + red[3];
    float r = rsqrtf(tot / (float)D_ + 1e-6f);
    const float4* s4 = (const float4*)scale;
    float4 sa = s4[threadIdx.x*2];
    float4 sb = s4[threadIdx.x*2 + 1];
    float v[8] = { sa.x*a.x, sa.y*a.y, sa.z*a.z, sa.w*a.w,
                   sb.x*b.x, sb.y*b.y, sb.z*b.z, sb.w*b.w };
    u16x8 o;
    #pragma unroll
    for (int j = 0; j < 8; ++j) {
        float t = fminf(fmaxf(v[j]*r, -60000.f), 60000.f);
        o[j] = f2bf(t);
    }
    ((u16x8*)(xn + (size_t)row * D_))[threadIdx.x] = o;
}

// ---------------- depthwise causal conv (K=4) + SiLU, 8 elems/thread ----------------
__global__ __launch_bounds__(256) void k_conv_silu(const __hip_bfloat16* __restrict__ xn,
                                                   const float* __restrict__ w,
                                                   const float* __restrict__ bias,
                                                   __hip_bfloat16* __restrict__ xc)
{
    size_t p = (size_t)blockIdx.x * 256 + threadIdx.x;  // over M*D/8
    size_t e0 = p * 8;
    int d0 = (int)(e0 & (D_-1));
    int n  = (int)((e0 >> 11) & (N_-1));
    const float4* w4 = (const float4*)w;               // w4[d] = weights of channel d
    float acc[8];
    const float4* b4 = (const float4*)(bias + d0);
    float4 ba = b4[0], bb = b4[1];
    acc[0]=ba.x; acc[1]=ba.y; acc[2]=ba.z; acc[3]=ba.w;
    acc[4]=bb.x; acc[5]=bb.y; acc[6]=bb.z; acc[7]=bb.w;
    float4 wv[8];
    #pragma unroll
    for (int j = 0; j < 8; ++j) wv[j] = w4[d0 + j];
    #pragma unroll
    for (int k = 0; k < 4; ++k) {
        int nn = n - 3 + k;
        if (nn >= 0) {
            u16x8 t = *(const u16x8*)(xn + e0 - (size_t)(3-k)*D_);
            #pragma unroll
            for (int j = 0; j < 8; ++j) {
                float wk = (k==0)?wv[j].x:(k==1)?wv[j].y:(k==2)?wv[j].z:wv[j].w;
                acc[j] += bf2f(t[j]) * wk;
            }
        }
    }
    u16x8 o;
    #pragma unroll
    for (int j = 0; j < 8; ++j) {
        float s = acc[j] / (1.f + __expf(-acc[j]));
        o[j] = f2bf(s);
    }
    *(u16x8*)(xc + e0) = o;
}

// ---------------- f32 -> bf16 cast (weights), 8 elems/thread ----------------
__global__ __launch_bounds__(256) void k_cast_bf16(const float* __restrict__ src,
                                                   __hip_bfloat16* __restrict__ dst)
{
    size_t p = (size_t)blockIdx.x * 256 + threadIdx.x;
    const float4* s4 = (const float4*)src;
    float4 a = s4[p*2], b = s4[p*2 + 1];
    u16x8 o;
    o[0]=f2bf(a.x); o[1]=f2bf(a.y); o[2]=f2bf(a.z); o[3]=f2bf(a.w);
    o[4]=f2bf(b.x); o[5]=f2bf(b.y); o[6]=f2bf(b.z); o[7]=f2bf(b.w);
    ((u16x8*)dst)[p] = o;
}

// ---------------- bf16 NT GEMM: acc[m][n] = sum_k A[m][k] * W[n][k] ----------------
// 128x128 tile, BK=64 (m97-verified config), 4 waves (2x2 quadrants of 64x64),
// mfma_f32_16x16x32_bf16, global_load_lds width=16 staging, 32 KiB LDS.
// MODE 0: in_proj — stream 0: la = -clip(softplus(acc+dt_bias[n]),0.001,2) (f32)
//                   stream 1: v raw (bf16);  stream 2: sigmoid -> gate (bf16)
// MODE 1: out_proj — out[off] = acc + resid[off]  (f32)
template<int MODE>
__global__ __launch_bounds__(256) void k_gemm(const __hip_bfloat16* __restrict__ Abf,
                                              const __hip_bfloat16* __restrict__ Wbf,
                                              int K,
                                              float* __restrict__ o0,
                                              __hip_bfloat16* __restrict__ o1,
                                              __hip_bfloat16* __restrict__ o2,
                                              const float* __restrict__ dt_bias,
                                              const float* __restrict__ resid,
                                              float* __restrict__ outp)
{
    __shared__ __attribute__((aligned(16))) __bf16 As[128*64];
    __shared__ __attribute__((aligned(16))) __bf16 Bs[128*64];
    const __bf16* A = (const __bf16*)Abf;
    const __bf16* W = (const __bf16*)Wbf;
    const int tid  = threadIdx.x;
    const int wave = tid >> 6;
    const int lane = tid & 63;
    const size_t m0 = (size_t)blockIdx.x * 128;
    const size_t n0 = (size_t)blockIdx.y * 128;
    const int wm = (wave & 1) * 64;
    const int wn = (wave >> 1) * 64;

    v4f acc[4][4] = {};

    const int fr = lane & 15;          // fragment row within 16x16
    const int kc = (lane >> 4) * 8;    // k-chunk (8 bf16)
    const int srow = lane >> 3;        // staging: 8 rows per issue, 8 lanes/row
    const int skol = (lane & 7) * 8;   // staging: 8 bf16 (16 B) per lane

    const int kIters = K >> 6;
    for (int kt = 0; kt < kIters; ++kt) {
        const int k0 = kt << 6;
        __syncthreads();
        // stage A-tile and B-tile: 4 issues each, wave-uniform LDS base + lane*16B
        #pragma unroll
        for (int i = 0; i < 4; ++i) {
            int rowbase = wave*32 + i*8;
            int row = rowbase + srow;
            async_copy16((void*)(As + rowbase*64),
                         (const void*)(A + (m0 + row)*(size_t)K + k0 + skol));
            async_copy16((void*)(Bs + rowbase*64),
                         (const void*)(W + (n0 + row)*(size_t)K + k0 + skol));
        }
        __syncthreads();

        #pragma unroll
        for (int kk = 0; kk < 2; ++kk) {
            v8bf fa[4], fb[4];
            #pragma unroll
            for (int i = 0; i < 4; ++i) {
                fa[i] = *(const v8bf*)(As + (wm + i*16 + fr)*64 + kk*32 + kc);
                fb[i] = *(const v8bf*)(Bs + (wn + i*16 + fr)*64 + kk*32 + kc);
            }
            #pragma unroll
            for (int i = 0; i < 4; ++i)
                #pragma unroll
                for (int j = 0; j < 4; ++j)
                    acc[i][j] = __builtin_amdgcn_mfma_f32_16x16x32_bf16(fa[i], fb[j], acc[i][j], 0, 0, 0);
        }
    }

    // epilogue: C/D layout col=lane&15, row=(lane>>4)*4+r  (m89-verified)
    const int col = lane & 15;
    const int rb  = (lane >> 4) * 4;
    if (MODE == 0) {
        const int stream = blockIdx.y >> 4;                 // 2048/128 = 16 blocks/stream
        const size_t nb = n0 - (size_t)stream * D_;
        #pragma unroll
        for (int i = 0; i < 4; ++i)
            #pragma unroll
            for (int j = 0; j < 4; ++j) {
                size_t nIdx = nb + wn + j*16 + col;
                #pragma unroll
                for (int r = 0; r < 4; ++r) {
                    size_t m = m0 + wm + i*16 + rb + r;
                    size_t off = m * (size_t)D_ + nIdx;
                    float v = acc[i][j][r];
                    if (stream == 0) {
                        float xx = v + dt_bias[nIdx];
                        float e  = __expf(-fabsf(xx));
                        float sp = fmaxf(xx, 0.f) + __logf(1.f + e);
                        float dt = fminf(fmaxf(sp, 0.001f), 2.0f);
                        o0[off] = -dt;                                    // log_alpha
                    } else if (stream == 1) {
                        o1[off] = __float2bfloat16(v);                    // raw v
                    } else {
                        o2[off] = __float2bfloat16(1.f/(1.f+__expf(-v))); // gate
                    }
                }
            }
    } else {
        #pragma unroll
        for (int i = 0; i < 4; ++i)
            #pragma unroll
            for (int j = 0; j < 4; ++j)
                #pragma unroll
                for (int r = 0; r < 4; ++r) {
                    size_t m = m0 + wm + i*16 + rb + r;
                    size_t off = m * (size_t)D_ + n0 + wn + j*16 + col;
                    outp[off] = acc[i][j][r] + resid[off];
                }
    }
}

// ---------------- scan phase 1: RoPE*dt fused; per (b,chunk,d) -> bd, bo ----------------
__global__ __launch_bounds__(256) void k_scan1(const float* __restrict__ la,
                                               const __hip_bfloat16* __restrict__ v,
                                               float* __restrict__ bd, float* __restrict__ bo)
{
    int idx = blockIdx.x * 256 + threadIdx.x;   // B*NC*D = 65536
    int d = idx & (D_-1);
    int c = (idx >> 11) & (NC_-1);
    int b = idx >> 15;
    int i = d & 63;
    const bool firstHalf = (d & 64) == 0;
    float inv = __expf((float)i * (-9.210340371976184f / 64.f)); // 10000^(-i/64)
    int n0 = c * CHUNK_;
    // incremental rotation: (cs,sn) = (cos,sin)(n*inv), step by inv
    float cs = cosf((float)n0 * inv), sn = sinf((float)n0 * inv);
    float ca = cosf(inv), sa = sinf(inv);
    size_t row0 = (size_t)b * N_ + (size_t)c * CHUNK_;
    float S = 0.f, Lp = 0.f, out = 0.f;
    #pragma unroll 8
    for (int t = 0; t < CHUNK_; ++t) {
        size_t off = (row0 + t) * (size_t)D_ + d;
        float a  = la[off];
        float vo = __bfloat162float(v[off]);
        float vp = __bfloat162float(v[firstHalf ? off + 64 : off - 64]);
        float dt = -a;
        float vin = (firstHalf ? (vo*cs - vp*sn) : (vp*sn + vo*cs)) * dt;
        S += a;
        float L = fmaxf(S, -20.f);           // clip(cumsum,-20,0): upper never binds
        out = __expf(L - Lp) * out + vin;
        Lp = L;
        float csn = cs*ca - sn*sa;           // advance angle by inv
        sn = sn*ca + cs*sa;
        cs = csn;
    }
    bd[idx] = Lp;
    bo[idx] = out;
}

// ---------------- scan phase 2: cross-chunk combine -> carries ----------------
__global__ __launch_bounds__(256) void k_scan2(const float* __restrict__ bd,
                                               const float* __restrict__ bo,
                                               float* __restrict__ carries)
{
    int idx = blockIdx.x * 256 + threadIdx.x;   // B*D = 4096
    int d = idx & (D_-1);
    int b = idx >> 11;
    float bd0 = bd[(size_t)(b*NC_)*D_ + d];     // stab = cd[0] = bd[0] (>= -20)
    float cd = 0.f, acc = 0.f;
    #pragma unroll
    for (int c = 0; c < NC_; ++c) {
        size_t o = (size_t)(b*NC_ + c)*D_ + d;
        cd = fmaxf(cd + bd[o], -80.f);          // clip(cumsum(bd),-80,0)
        float ncd = fmaxf(cd - bd0, -20.f);     // clip(cd-stab,-20,0)
        carries[o] = acc * __expf(ncd);         // sum of seeds STRICTLY BEFORE c
        acc += bo[o] * __expf(-ncd);
    }
}

// ---------------- scan phase 3: recompute + carry; write state (bf16) ----------------
__global__ __launch_bounds__(256) void k_scan3(const float* __restrict__ la,
                                               const __hip_bfloat16* __restrict__ v,
                                               const float* __restrict__ carries,
                                               __hip_bfloat16* __restrict__ state)
{
    int idx = blockIdx.x * 256 + threadIdx.x;
    int d = idx & (D_-1);
    int c = (idx >> 11) & (NC_-1);
    int b = idx >> 15;
    int i = d & 63;
    const bool firstHalf = (d & 64) == 0;
    float inv = __expf((float)i * (-9.210340371976184f / 64.f));
    int n0 = c * CHUNK_;
    float cs = cosf((float)n0 * inv), sn = sinf((float)n0 * inv);
    float ca = cosf(inv), sa = sinf(inv);
    float carry = carries[idx];
    size_t row0 = (size_t)b * N_ + (size_t)c * CHUNK_;
    float S = 0.f, Lp = 0.f, out = 0.f;
    #pragma unroll 8
    for (int t = 0; t < CHUNK_; ++t) {
        size_t off = (row0 + t) * (size_t)D_ + d;
        float a  = la[off];
        float vo = __bfloat162float(v[off]);
        float vp = __bfloat162float(v[firstHalf ? off + 64 : off - 64]);
        float dt = -a;
        float vin = (firstHalf ? (vo*cs - vp*sn) : (vp*sn + vo*cs)) * dt;
        S += a;
        float L = fmaxf(S, -20.f);
        out = __expf(L - Lp) * out + vin;
        Lp = L;
        state[off] = __float2bfloat16(out + carry * __expf(L));
        float csn = cs*ca - sn*sa;
        sn = sn*ca + cs*sa;
        cs = csn;
    }
}

// ---------------- head_mix (generic 16x16) * gate -> y (bf16) ----------------
__global__ __launch_bounds__(256) void k_headmix_gate(const __hip_bfloat16* __restrict__ state,
                                                      const __hip_bfloat16* __restrict__ gate,
                                                      const float* __restrict__ hm,
                                                      __hip_bfloat16* __restrict__ y)
{
    __shared__ float lf[D_];
    __shared__ float lhm[H_*H_];
    const int row = blockIdx.x;
    const size_t base = (size_t)row * D_;
    u16x8 s8 = ((const u16x8*)(state + base))[threadIdx.x];
    #pragma unroll
    for (int j = 0; j < 8; ++j) lf[threadIdx.x*8 + j] = bf2f(s8[j]);
    if (threadIdx.x < H_*H_) lhm[threadIdx.x] = hm[threadIdx.x];
    __syncthreads();
    #pragma unroll
    for (int k = 0; k < 8; ++k) {
        int o = threadIdx.x + k*256;
        int m  = o >> 7;
        int dh = o & 127;
        float s = 0.f;
        #pragma unroll
        for (int h = 0; h < H_; ++h) s += lf[h*DH_ + dh] * lhm[h*H_ + m];
        float g = __bfloat162float(gate[base + o]);
        y[base + o] = __float2bfloat16(s * g);
    }
}

extern "C" void kernel_launch(void* const* d_in, const int* in_sizes, int n_in,
                              void* d_out, int out_size, void* d_ws, size_t ws_size,
                              hipStream_t stream)
{
    const float* x          = (const float*)d_in[0];
    const float* norm_scale = (const float*)d_in[1];
    const float* conv_w     = (const float*)d_in[2];
    const float* conv_b     = (const float*)d_in[3];
    const float* in_proj_w  = (const float*)d_in[4];
    const float* dt_bias    = (const float*)d_in[5];
    const float* head_mix   = (const float*)d_in[6];
    const float* out_proj_w = (const float*)d_in[7];
    float* out = (float*)d_out;

    // Workspace layout — total 176,947,200 B.
    char* ws = (char*)d_ws;
    float*          la   = (float*)ws;                               // 67,108,864 B (log_alpha, f32)
    __hip_bfloat16* xn   = (__hip_bfloat16*)(ws + 67108864);         // 33,554,432 B; reused for w1 after conv
    __hip_bfloat16* xc   = (__hip_bfloat16*)(ws + 100663296);        // 33,554,432 B; reused for y after GEMM1
    __hip_bfloat16* gate = (__hip_bfloat16*)(ws + 134217728);        // 33,554,432 B
    __hip_bfloat16* w2   = (__hip_bfloat16*)(ws + 167772160);        //  8,388,608 B
    float*          bd   = (float*)(ws + 176160768);                 //    262,144 B
    float*          bo   = (float*)(ws + 176422912);                 //    262,144 B
    float*          carr = (float*)(ws + 176685056);                 //    262,144 B
    __hip_bfloat16* w1   = xn;   // xn dead after conv
    __hip_bfloat16* y    = xc;   // xc dead after GEMM1
    // d_out as staged scratch: v (bf16, first half) and state (bf16, second half),
    // both fully dead before GEMM2 overwrites d_out with the final f32 output.
    __hip_bfloat16* v     = (__hip_bfloat16*)d_out;
    __hip_bfloat16* state = (__hip_bfloat16*)((char*)d_out + 33554432);

    k_rmsnorm<<<M_, 256, 0, stream>>>(x, norm_scale, xn);
    k_conv_silu<<<(M_*(size_t)D_)/8/256, 256, 0, stream>>>(xn, conv_w, conv_b, xc);
    k_cast_bf16<<<6144, 256, 0, stream>>>(in_proj_w, w1);
    k_cast_bf16<<<2048, 256, 0, stream>>>(out_proj_w, w2);
    k_gemm<0><<<dim3(M_/128, F3D/128), 256, 0, stream>>>(xc, w1, D_, la, v, gate, dt_bias, nullptr, nullptr);
    k_scan1<<<(B_*NC_*D_)/256, 256, 0, stream>>>(la, v, bd, bo);
    k_scan2<<<(B_*D_)/256, 256, 0, stream>>>(bd, bo, carr);
    k_scan3<<<(B_*NC_*D_)/256, 256, 0, stream>>>(la, v, carr, state);
    k_headmix_gate<<<M_, 256, 0, stream>>>(state, gate, head_mix, y);
    k_gemm<1><<<dim3(M_/128, D_/128), 256, 0, stream>>>(y, w2, D_, nullptr, nullptr, nullptr, nullptr, x, out);
}

// Round 2
// 719.049 us; speedup vs baseline: 1.1527x; 1.1321x over previous
//
#include <hip/hip_runtime.h>
#include <hip/hip_bf16.h>
#include <math.h>

// Problem constants (fixed by setup_inputs)
#define B_ 2
#define N_ 4096
#define D_ 2048
#define H_ 16
#define DH_ 128
#define CHUNK_ 256
#define NC_ 16
#define M_ (B_*N_)          // 8192 tokens
#define F3D (3*D_)          // 6144

typedef __bf16 v8bf __attribute__((ext_vector_type(8)));
typedef float  v4f  __attribute__((ext_vector_type(4)));
typedef unsigned short u16x8 __attribute__((ext_vector_type(8)));

__device__ __forceinline__ float bf2f(unsigned short u) {
    union { unsigned int i; float f; } c; c.i = ((unsigned int)u) << 16; return c.f;
}
__device__ __forceinline__ unsigned short f2bf(float f) {
    __hip_bfloat16 h = __float2bfloat16(f);
    return *(unsigned short*)&h;
}

__device__ __forceinline__ void async_copy16(void* lds, const void* g) {
    __builtin_amdgcn_global_load_lds(
        (const __attribute__((address_space(1))) unsigned int*)g,
        (__attribute__((address_space(3))) unsigned int*)lds,
        16, 0, 0);
}

// ---------------- RMSNorm: x (f32) -> xn (bf16), 8 elems/thread ----------------
__global__ __launch_bounds__(256) void k_rmsnorm(const float* __restrict__ x,
                                                 const float* __restrict__ scale,
                                                 __hip_bfloat16* __restrict__ xn)
{
    __shared__ float red[4];
    const int row = blockIdx.x;
    const float4* x4 = (const float4*)(x + (size_t)row * D_);
    float4 a = x4[threadIdx.x*2];
    float4 b = x4[threadIdx.x*2 + 1];
    float ss = a.x*a.x + a.y*a.y + a.z*a.z + a.w*a.w
             + b.x*b.x + b.y*b.y + b.z*b.z + b.w*b.w;
    #pragma unroll
    for (int off = 32; off > 0; off >>= 1) ss += __shfl_down(ss, off, 64);
    if ((threadIdx.x & 63) == 0) red[threadIdx.x >> 6] = ss;
    __syncthreads();
    float tot = red[0] + red[1] + red[2] + red[3];
    float r = rsqrtf(tot / (float)D_ + 1e-6f);
    const float4* s4 = (const float4*)scale;
    float4 sa = s4[threadIdx.x*2];
    float4 sb = s4[threadIdx.x*2 + 1];
    float v[8] = { sa.x*a.x, sa.y*a.y, sa.z*a.z, sa.w*a.w,
                   sb.x*b.x, sb.y*b.y, sb.z*b.z, sb.w*b.w };
    u16x8 o;
    #pragma unroll
    for (int j = 0; j < 8; ++j) {
        float t = fminf(fmaxf(v[j]*r, -60000.f), 60000.f);
        o[j] = f2bf(t);
    }
    ((u16x8*)(xn + (size_t)row * D_))[threadIdx.x] = o;
}

// ---------------- depthwise causal conv (K=4) + SiLU, 8 elems/thread ----------------
__global__ __launch_bounds__(256) void k_conv_silu(const __hip_bfloat16* __restrict__ xn,
                                                   const float* __restrict__ w,
                                                   const float* __restrict__ bias,
                                                   __hip_bfloat16* __restrict__ xc)
{
    size_t p = (size_t)blockIdx.x * 256 + threadIdx.x;  // over M*D/8
    size_t e0 = p * 8;
    int d0 = (int)(e0 & (D_-1));
    int n  = (int)((e0 >> 11) & (N_-1));
    const float4* w4 = (const float4*)w;               // w4[d] = weights of channel d
    float acc[8];
    const float4* b4 = (const float4*)(bias + d0);
    float4 ba = b4[0], bb = b4[1];
    acc[0]=ba.x; acc[1]=ba.y; acc[2]=ba.z; acc[3]=ba.w;
    acc[4]=bb.x; acc[5]=bb.y; acc[6]=bb.z; acc[7]=bb.w;
    float4 wv[8];
    #pragma unroll
    for (int j = 0; j < 8; ++j) wv[j] = w4[d0 + j];
    #pragma unroll
    for (int k = 0; k < 4; ++k) {
        int nn = n - 3 + k;
        if (nn >= 0) {
            u16x8 t = *(const u16x8*)(xn + e0 - (size_t)(3-k)*D_);
            #pragma unroll
            for (int j = 0; j < 8; ++j) {
                float wk = (k==0)?wv[j].x:(k==1)?wv[j].y:(k==2)?wv[j].z:wv[j].w;
                acc[j] += bf2f(t[j]) * wk;
            }
        }
    }
    u16x8 o;
    #pragma unroll
    for (int j = 0; j < 8; ++j) {
        float s = acc[j] / (1.f + __expf(-acc[j]));
        o[j] = f2bf(s);
    }
    *(u16x8*)(xc + e0) = o;
}

// ---------------- f32 -> bf16 cast (weights), 8 elems/thread ----------------
__global__ __launch_bounds__(256) void k_cast_bf16(const float* __restrict__ src,
                                                   __hip_bfloat16* __restrict__ dst)
{
    size_t p = (size_t)blockIdx.x * 256 + threadIdx.x;
    const float4* s4 = (const float4*)src;
    float4 a = s4[p*2], b = s4[p*2 + 1];
    u16x8 o;
    o[0]=f2bf(a.x); o[1]=f2bf(a.y); o[2]=f2bf(a.z); o[3]=f2bf(a.w);
    o[4]=f2bf(b.x); o[5]=f2bf(b.y); o[6]=f2bf(b.z); o[7]=f2bf(b.w);
    ((u16x8*)dst)[p] = o;
}

// ---------------- bf16 NT GEMM: acc[m][n] = sum_k A[m][k] * W[n][k] ----------------
// 256x256 tile, BK=32, 8 waves (2M x 4N, per-wave 128x64 output), depth-2 pipeline:
//   3 LDS buffers (96 KiB); during tile t stage tile t+2; tile-boundary wait is
//   counted vmcnt(4) (stages(t+1) stay in flight across barriers) — T3+T4.
//   LDS XOR-swizzle col16 ^= (row>>1)&3 applied on pre-swizzled global source
//   (linear global_load_lds dest) AND ds_read address — T2, rule #21 compliant.
//   setprio(1) around each 16-MFMA cluster — T5. XCD-bijective block swizzle — T1.
// Ledger: prologue issues stages(0)+stages(1) = 8 outstanding/wave.
//   top of tile t: outstanding = stages(t)[4] + stages(t+1)[4] -> vmcnt(4)
//   retires stages(t); per-wave wait then s_barrier makes all waves' data visible.
// MODE 0: in_proj — stream 0: la = -clip(softplus(acc+dt_bias[n]),0.001,2) (f32)
//                   stream 1: v raw (bf16);  stream 2: sigmoid -> gate (bf16)
// MODE 1: out_proj — out[off] = acc + resid[off]  (f32)
template<int MODE>
__global__ __launch_bounds__(512, 2) void k_gemm(const __hip_bfloat16* __restrict__ Abf,
                                              const __hip_bfloat16* __restrict__ Wbf,
                                              int K,
                                              float* __restrict__ o0,
                                              __hip_bfloat16* __restrict__ o1,
                                              __hip_bfloat16* __restrict__ o2,
                                              const float* __restrict__ dt_bias,
                                              const float* __restrict__ resid,
                                              float* __restrict__ outp)
{
    // [buf 0..2][A=0/B=1][256 rows x 32 cols bf16 = 16 KiB]
    __shared__ __attribute__((aligned(16))) char lds[3][2][16384];
    const __bf16* A = (const __bf16*)Abf;
    const __bf16* W = (const __bf16*)Wbf;
    const int tid  = threadIdx.x;
    const int wave = tid >> 6;
    const int lane = tid & 63;

    // T1: bijective XCD swizzle over linearized grid (nwg % 8 == 0 for all call sites)
    const int gx  = gridDim.x;
    int bid = blockIdx.y * gx + blockIdx.x;
    int cpx = (gx * gridDim.y) >> 3;
    int swzb = (bid & 7) * cpx + (bid >> 3);
    int bx = swzb % gx, by = swzb / gx;

    const size_t m0 = (size_t)bx * 256;
    const size_t n0 = (size_t)by * 256;
    const int wm = (wave & 1) * 128;      // 2 waves in M
    const int wn = (wave >> 1) * 64;      // 4 waves in N

    v4f acc[8][4] = {};

    // ---- read-side addressing (swizzled) ----
    const int fr = lane & 15;             // fragment row within 16
    const int qk = lane >> 4;             // k 16B-chunk 0..3
    const int colb = ((qk ^ ((fr >> 1) & 3)) << 4);   // swizzled byte col
    int rowA[8], rowB[4];
    #pragma unroll
    for (int i = 0; i < 8; ++i) rowA[i] = (wm + i*16 + fr) * 64;
    #pragma unroll
    for (int j = 0; j < 4; ++j) rowB[j] = (wn + j*16 + fr) * 64;

    // ---- stage-side addressing (linear LDS dest, pre-swizzled global src) ----
    const int rowi   = tid >> 2;          // 0..127 rows per 8 KiB issue
    const int col16s = tid & 3;           // 16B slot within 64 B row
    const int scol   = (col16s ^ ((rowi >> 1) & 3)) * 8;  // src element offset

    const int nt = K >> 5;                // BK=32

    // stage one 8 KiB half (128 rows) of A or B of tile t into buf[t%3]
    auto stage = [&](int t, int half, int isB) {
        char* dst = lds[t % 3][isB] + (half * 8192 + wave * 1024);
        int rfull = half * 128 + rowi;
        size_t grow = (isB ? n0 : m0) + (size_t)rfull;
        const __bf16* src = (isB ? W : A) + grow * (size_t)K + (t << 5) + scol;
        async_copy16((void*)dst, (const void*)src);
    };

    // prologue: stages(0) + stages(1) -> 8 outstanding per wave
    #pragma unroll
    for (int h = 0; h < 2; ++h) { stage(0, h, 0); stage(0, h, 1); }
    #pragma unroll
    for (int h = 0; h < 2; ++h) { stage(1, h, 0); stage(1, h, 1); }

    for (int t = 0; t < nt; ++t) {
        if (t + 1 < nt) { asm volatile("s_waitcnt vmcnt(4)" ::: "memory"); }
        else            { asm volatile("s_waitcnt vmcnt(0)" ::: "memory"); }
        __builtin_amdgcn_sched_barrier(0);
        __builtin_amdgcn_s_barrier();      // all waves' stages(t) now visible

        const char* Ab = lds[t % 3][0];
        const char* Bb = lds[t % 3][1];
        const bool pf = (t + 2) < nt;
        const int  t2 = t + 2;

        v8bf fa[4], fb[4], fa2[4];

        // ---- phase 1: stage A(t+2) || read A(i0-3)+B(j0-3) || MFMA i0-3 x j0-3
        if (pf) { stage(t2, 0, 0); stage(t2, 1, 0); }
        #pragma unroll
        for (int i = 0; i < 4; ++i) fa[i] = *(const v8bf*)(Ab + rowA[i] + colb);
        #pragma unroll
        for (int j = 0; j < 4; ++j) fb[j] = *(const v8bf*)(Bb + rowB[j] + colb);
        __builtin_amdgcn_s_barrier();
        __builtin_amdgcn_s_setprio(1);
        #pragma unroll
        for (int i = 0; i < 4; ++i)
            #pragma unroll
            for (int j = 0; j < 4; ++j)
                acc[i][j] = __builtin_amdgcn_mfma_f32_16x16x32_bf16(fa[i], fb[j], acc[i][j], 0, 0, 0);
        __builtin_amdgcn_s_setprio(0);
        __builtin_amdgcn_s_barrier();

        // ---- phase 2: stage B(t+2) || read A(i4-7) || MFMA i4-7 x j0-3
        if (pf) { stage(t2, 0, 1); stage(t2, 1, 1); }
        #pragma unroll
        for (int i = 0; i < 4; ++i) fa2[i] = *(const v8bf*)(Ab + rowA[4 + i] + colb);
        __builtin_amdgcn_s_barrier();
        __builtin_amdgcn_s_setprio(1);
        #pragma unroll
        for (int i = 0; i < 4; ++i)
            #pragma unroll
            for (int j = 0; j < 4; ++j)
                acc[4 + i][j] = __builtin_amdgcn_mfma_f32_16x16x32_bf16(fa2[i], fb[j], acc[4 + i][j], 0, 0, 0);
        __builtin_amdgcn_s_setprio(0);
        __builtin_amdgcn_s_barrier();
    }

    // epilogue: C/D layout col=lane&15, row=(lane>>4)*4+r  (m89-verified)
    const int col = lane & 15;
    const int rb  = (lane >> 4) * 4;
    if (MODE == 0) {
        const int stream = by >> 3;                 // 2048/256 = 8 blocks/stream
        const size_t nb = n0 - (size_t)stream * D_;
        #pragma unroll
        for (int i = 0; i < 8; ++i)
            #pragma unroll
            for (int j = 0; j < 4; ++j) {
                size_t nIdx = nb + wn + j*16 + col;
                #pragma unroll
                for (int r = 0; r < 4; ++r) {
                    size_t m = m0 + wm + i*16 + rb + r;
                    size_t off = m * (size_t)D_ + nIdx;
                    float v = acc[i][j][r];
                    if (stream == 0) {
                        float xx = v + dt_bias[nIdx];
                        float e  = __expf(-fabsf(xx));
                        float sp = fmaxf(xx, 0.f) + __logf(1.f + e);
                        float dt = fminf(fmaxf(sp, 0.001f), 2.0f);
                        o0[off] = -dt;                                    // log_alpha
                    } else if (stream == 1) {
                        o1[off] = __float2bfloat16(v);                    // raw v
                    } else {
                        o2[off] = __float2bfloat16(1.f/(1.f+__expf(-v))); // gate
                    }
                }
            }
    } else {
        #pragma unroll
        for (int i = 0; i < 8; ++i)
            #pragma unroll
            for (int j = 0; j < 4; ++j)
                #pragma unroll
                for (int r = 0; r < 4; ++r) {
                    size_t m = m0 + wm + i*16 + rb + r;
                    size_t off = m * (size_t)D_ + n0 + wn + j*16 + col;
                    outp[off] = acc[i][j][r] + resid[off];
                }
    }
}

// ---------------- scan phase 1: RoPE*dt fused; per (b,chunk,d) -> bd, bo ----------------
__global__ __launch_bounds__(256) void k_scan1(const float* __restrict__ la,
                                               const __hip_bfloat16* __restrict__ v,
                                               float* __restrict__ bd, float* __restrict__ bo)
{
    int idx = blockIdx.x * 256 + threadIdx.x;   // B*NC*D = 65536
    int d = idx & (D_-1);
    int c = (idx >> 11) & (NC_-1);
    int b = idx >> 15;
    int i = d & 63;
    const bool firstHalf = (d & 64) == 0;
    float inv = __expf((float)i * (-9.210340371976184f / 64.f)); // 10000^(-i/64)
    int n0 = c * CHUNK_;
    // incremental rotation: (cs,sn) = (cos,sin)(n*inv), step by inv
    float cs = cosf((float)n0 * inv), sn = sinf((float)n0 * inv);
    float ca = cosf(inv), sa = sinf(inv);
    size_t row0 = (size_t)b * N_ + (size_t)c * CHUNK_;
    float S = 0.f, Lp = 0.f, out = 0.f;
    #pragma unroll 8
    for (int t = 0; t < CHUNK_; ++t) {
        size_t off = (row0 + t) * (size_t)D_ + d;
        float a  = la[off];
        float vo = __bfloat162float(v[off]);
        float vp = __bfloat162float(v[firstHalf ? off + 64 : off - 64]);
        float dt = -a;
        float vin = (firstHalf ? (vo*cs - vp*sn) : (vp*sn + vo*cs)) * dt;
        S += a;
        float L = fmaxf(S, -20.f);           // clip(cumsum,-20,0): upper never binds
        out = __expf(L - Lp) * out + vin;
        Lp = L;
        float csn = cs*ca - sn*sa;           // advance angle by inv
        sn = sn*ca + cs*sa;
        cs = csn;
    }
    bd[idx] = Lp;
    bo[idx] = out;
}

// ---------------- scan phase 2: cross-chunk combine -> carries ----------------
__global__ __launch_bounds__(256) void k_scan2(const float* __restrict__ bd,
                                               const float* __restrict__ bo,
                                               float* __restrict__ carries)
{
    int idx = blockIdx.x * 256 + threadIdx.x;   // B*D = 4096
    int d = idx & (D_-1);
    int b = idx >> 11;
    float bd0 = bd[(size_t)(b*NC_)*D_ + d];     // stab = cd[0] = bd[0] (>= -20)
    float cd = 0.f, acc = 0.f;
    #pragma unroll
    for (int c = 0; c < NC_; ++c) {
        size_t o = (size_t)(b*NC_ + c)*D_ + d;
        cd = fmaxf(cd + bd[o], -80.f);          // clip(cumsum(bd),-80,0)
        float ncd = fmaxf(cd - bd0, -20.f);     // clip(cd-stab,-20,0)
        carries[o] = acc * __expf(ncd);         // sum of seeds STRICTLY BEFORE c
        acc += bo[o] * __expf(-ncd);
    }
}

// ---------------- scan phase 3: recompute + carry; write state (bf16) ----------------
__global__ __launch_bounds__(256) void k_scan3(const float* __restrict__ la,
                                               const __hip_bfloat16* __restrict__ v,
                                               const float* __restrict__ carries,
                                               __hip_bfloat16* __restrict__ state)
{
    int idx = blockIdx.x * 256 + threadIdx.x;
    int d = idx & (D_-1);
    int c = (idx >> 11) & (NC_-1);
    int b = idx >> 15;
    int i = d & 63;
    const bool firstHalf = (d & 64) == 0;
    float inv = __expf((float)i * (-9.210340371976184f / 64.f));
    int n0 = c * CHUNK_;
    float cs = cosf((float)n0 * inv), sn = sinf((float)n0 * inv);
    float ca = cosf(inv), sa = sinf(inv);
    float carry = carries[idx];
    size_t row0 = (size_t)b * N_ + (size_t)c * CHUNK_;
    float S = 0.f, Lp = 0.f, out = 0.f;
    #pragma unroll 8
    for (int t = 0; t < CHUNK_; ++t) {
        size_t off = (row0 + t) * (size_t)D_ + d;
        float a  = la[off];
        float vo = __bfloat162float(v[off]);
        float vp = __bfloat162float(v[firstHalf ? off + 64 : off - 64]);
        float dt = -a;
        float vin = (firstHalf ? (vo*cs - vp*sn) : (vp*sn + vo*cs)) * dt;
        S += a;
        float L = fmaxf(S, -20.f);
        out = __expf(L - Lp) * out + vin;
        Lp = L;
        state[off] = __float2bfloat16(out + carry * __expf(L));
        float csn = cs*ca - sn*sa;
        sn = sn*ca + cs*sa;
        cs = csn;
    }
}

// ---------------- head_mix (generic 16x16) * gate -> y (bf16) ----------------
__global__ __launch_bounds__(256) void k_headmix_gate(const __hip_bfloat16* __restrict__ state,
                                                      const __hip_bfloat16* __restrict__ gate,
                                                      const float* __restrict__ hm,
                                                      __hip_bfloat16* __restrict__ y)
{
    __shared__ float lf[D_];
    __shared__ float lhm[H_*H_];
    const int row = blockIdx.x;
    const size_t base = (size_t)row * D_;
    u16x8 s8 = ((const u16x8*)(state + base))[threadIdx.x];
    #pragma unroll
    for (int j = 0; j < 8; ++j) lf[threadIdx.x*8 + j] = bf2f(s8[j]);
    if (threadIdx.x < H_*H_) lhm[threadIdx.x] = hm[threadIdx.x];
    __syncthreads();
    #pragma unroll
    for (int k = 0; k < 8; ++k) {
        int o = threadIdx.x + k*256;
        int m  = o >> 7;
        int dh = o & 127;
        float s = 0.f;
        #pragma unroll
        for (int h = 0; h < H_; ++h) s += lf[h*DH_ + dh] * lhm[h*H_ + m];
        float g = __bfloat162float(gate[base + o]);
        y[base + o] = __float2bfloat16(s * g);
    }
}

extern "C" void kernel_launch(void* const* d_in, const int* in_sizes, int n_in,
                              void* d_out, int out_size, void* d_ws, size_t ws_size,
                              hipStream_t stream)
{
    const float* x          = (const float*)d_in[0];
    const float* norm_scale = (const float*)d_in[1];
    const float* conv_w     = (const float*)d_in[2];
    const float* conv_b     = (const float*)d_in[3];
    const float* in_proj_w  = (const float*)d_in[4];
    const float* dt_bias    = (const float*)d_in[5];
    const float* head_mix   = (const float*)d_in[6];
    const float* out_proj_w = (const float*)d_in[7];
    float* out = (float*)d_out;

    // Workspace layout — total 176,947,200 B.
    char* ws = (char*)d_ws;
    float*          la   = (float*)ws;                               // 67,108,864 B (log_alpha, f32)
    __hip_bfloat16* xn   = (__hip_bfloat16*)(ws + 67108864);         // 33,554,432 B; reused for w1 after conv
    __hip_bfloat16* xc   = (__hip_bfloat16*)(ws + 100663296);        // 33,554,432 B; reused for y after GEMM1
    __hip_bfloat16* gate = (__hip_bfloat16*)(ws + 134217728);        // 33,554,432 B
    __hip_bfloat16* w2   = (__hip_bfloat16*)(ws + 167772160);        //  8,388,608 B
    float*          bd   = (float*)(ws + 176160768);                 //    262,144 B
    float*          bo   = (float*)(ws + 176422912);                 //    262,144 B
    float*          carr = (float*)(ws + 176685056);                 //    262,144 B
    __hip_bfloat16* w1   = xn;   // xn dead after conv
    __hip_bfloat16* y    = xc;   // xc dead after GEMM1
    // d_out as staged scratch: v (bf16, first half) and state (bf16, second half),
    // both fully dead before GEMM2 overwrites d_out with the final f32 output.
    __hip_bfloat16* v     = (__hip_bfloat16*)d_out;
    __hip_bfloat16* state = (__hip_bfloat16*)((char*)d_out + 33554432);

    k_rmsnorm<<<M_, 256, 0, stream>>>(x, norm_scale, xn);
    k_conv_silu<<<(M_*(size_t)D_)/8/256, 256, 0, stream>>>(xn, conv_w, conv_b, xc);
    k_cast_bf16<<<6144, 256, 0, stream>>>(in_proj_w, w1);
    k_cast_bf16<<<2048, 256, 0, stream>>>(out_proj_w, w2);
    k_gemm<0><<<dim3(M_/256, F3D/256), 512, 0, stream>>>(xc, w1, D_, la, v, gate, dt_bias, nullptr, nullptr);
    k_scan1<<<(B_*NC_*D_)/256, 256, 0, stream>>>(la, v, bd, bo);
    k_scan2<<<(B_*D_)/256, 256, 0, stream>>>(bd, bo, carr);
    k_scan3<<<(B_*NC_*D_)/256, 256, 0, stream>>>(la, v, carr, state);
    k_headmix_gate<<<M_, 256, 0, stream>>>(state, gate, head_mix, y);
    k_gemm<1><<<dim3(M_/256, D_/256), 512, 0, stream>>>(y, w2, D_, nullptr, nullptr, nullptr, nullptr, x, out);
}

// Round 3
// 713.240 us; speedup vs baseline: 1.1620x; 1.0081x over previous
//
#include <hip/hip_runtime.h>
#include <hip/hip_bf16.h>
#include <math.h>

// Problem constants (fixed by setup_inputs)
#define B_ 2
#define N_ 4096
#define D_ 2048
#define H_ 16
#define DH_ 128
#define CHUNK_ 256
#define NC_ 16
#define M_ (B_*N_)          // 8192 tokens
#define F3D (3*D_)          // 6144

typedef __bf16 v8bf __attribute__((ext_vector_type(8)));
typedef float  v4f  __attribute__((ext_vector_type(4)));
typedef unsigned short u16x8 __attribute__((ext_vector_type(8)));

__device__ __forceinline__ float bf2f(unsigned short u) {
    union { unsigned int i; float f; } c; c.i = ((unsigned int)u) << 16; return c.f;
}
__device__ __forceinline__ unsigned short f2bf(float f) {
    __hip_bfloat16 h = __float2bfloat16(f);
    return *(unsigned short*)&h;
}

__device__ __forceinline__ void async_copy16(void* lds, const void* g) {
    __builtin_amdgcn_global_load_lds(
        (const __attribute__((address_space(1))) unsigned int*)g,
        (__attribute__((address_space(3))) unsigned int*)lds,
        16, 0, 0);
}

// ---------------- RMSNorm: x (f32) -> xn (bf16), 8 elems/thread ----------------
__global__ __launch_bounds__(256) void k_rmsnorm(const float* __restrict__ x,
                                                 const float* __restrict__ scale,
                                                 __hip_bfloat16* __restrict__ xn)
{
    __shared__ float red[4];
    const int row = blockIdx.x;
    const float4* x4 = (const float4*)(x + (size_t)row * D_);
    float4 a = x4[threadIdx.x*2];
    float4 b = x4[threadIdx.x*2 + 1];
    float ss = a.x*a.x + a.y*a.y + a.z*a.z + a.w*a.w
             + b.x*b.x + b.y*b.y + b.z*b.z + b.w*b.w;
    #pragma unroll
    for (int off = 32; off > 0; off >>= 1) ss += __shfl_down(ss, off, 64);
    if ((threadIdx.x & 63) == 0) red[threadIdx.x >> 6] = ss;
    __syncthreads();
    float tot = red[0] + red[1] + red[2] + red[3];
    float r = rsqrtf(tot / (float)D_ + 1e-6f);
    const float4* s4 = (const float4*)scale;
    float4 sa = s4[threadIdx.x*2];
    float4 sb = s4[threadIdx.x*2 + 1];
    float v[8] = { sa.x*a.x, sa.y*a.y, sa.z*a.z, sa.w*a.w,
                   sb.x*b.x, sb.y*b.y, sb.z*b.z, sb.w*b.w };
    u16x8 o;
    #pragma unroll
    for (int j = 0; j < 8; ++j) {
        float t = fminf(fmaxf(v[j]*r, -60000.f), 60000.f);
        o[j] = f2bf(t);
    }
    ((u16x8*)(xn + (size_t)row * D_))[threadIdx.x] = o;
}

// ---------------- depthwise causal conv (K=4) + SiLU, 8 elems/thread ----------------
__global__ __launch_bounds__(256) void k_conv_silu(const __hip_bfloat16* __restrict__ xn,
                                                   const float* __restrict__ w,
                                                   const float* __restrict__ bias,
                                                   __hip_bfloat16* __restrict__ xc)
{
    size_t p = (size_t)blockIdx.x * 256 + threadIdx.x;  // over M*D/8
    size_t e0 = p * 8;
    int d0 = (int)(e0 & (D_-1));
    int n  = (int)((e0 >> 11) & (N_-1));
    const float4* w4 = (const float4*)w;               // w4[d] = weights of channel d
    float acc[8];
    const float4* b4 = (const float4*)(bias + d0);
    float4 ba = b4[0], bb = b4[1];
    acc[0]=ba.x; acc[1]=ba.y; acc[2]=ba.z; acc[3]=ba.w;
    acc[4]=bb.x; acc[5]=bb.y; acc[6]=bb.z; acc[7]=bb.w;
    float4 wv[8];
    #pragma unroll
    for (int j = 0; j < 8; ++j) wv[j] = w4[d0 + j];
    #pragma unroll
    for (int k = 0; k < 4; ++k) {
        int nn = n - 3 + k;
        if (nn >= 0) {
            u16x8 t = *(const u16x8*)(xn + e0 - (size_t)(3-k)*D_);
            #pragma unroll
            for (int j = 0; j < 8; ++j) {
                float wk = (k==0)?wv[j].x:(k==1)?wv[j].y:(k==2)?wv[j].z:wv[j].w;
                acc[j] += bf2f(t[j]) * wk;
            }
        }
    }
    u16x8 o;
    #pragma unroll
    for (int j = 0; j < 8; ++j) {
        float s = acc[j] / (1.f + __expf(-acc[j]));
        o[j] = f2bf(s);
    }
    *(u16x8*)(xc + e0) = o;
}

// ---------------- f32 -> bf16 cast (weights), 8 elems/thread ----------------
__global__ __launch_bounds__(256) void k_cast_bf16(const float* __restrict__ src,
                                                   __hip_bfloat16* __restrict__ dst)
{
    size_t p = (size_t)blockIdx.x * 256 + threadIdx.x;
    const float4* s4 = (const float4*)src;
    float4 a = s4[p*2], b = s4[p*2 + 1];
    u16x8 o;
    o[0]=f2bf(a.x); o[1]=f2bf(a.y); o[2]=f2bf(a.z); o[3]=f2bf(a.w);
    o[4]=f2bf(b.x); o[5]=f2bf(b.y); o[6]=f2bf(b.z); o[7]=f2bf(b.w);
    ((u16x8*)dst)[p] = o;
}

// ---------------- bf16 NT GEMM: acc[m][n] = sum_k A[m][k] * W[n][k] ----------------
// 256x256 tile, BK=32, 8 waves (2M x 4N, per-wave 128x64 output), depth-2 pipeline.
// BARRIER-MINIMAL schedule (round-3 change): 3 LDS buffers (96 KiB) make all
// intra-tile barriers unnecessary — the staged buffer (t+2)%3 is never a buffer
// being read (t%3 or (t+1)%3), and each wave's reads of buf (t-1)%3 are consumed
// (lgkmcnt-enforced before MFMA use) before it reaches the top-of-tile barrier.
// Per tile: { counted vmcnt(4); s_barrier } then free-running
// { 4x global_load_lds stage(t+2) || 12x ds_read_b128 || 32x MFMA } with
// compiler fine-grained lgkmcnt scheduling + wave-level MFMA/LDS overlap (m114).
// Counted vmcnt never drains to 0 in the main loop (T4).
// LDS XOR-swizzle col16 ^= (row>>1)&3 on pre-swizzled global source (linear
// global_load_lds dest) AND ds_read address — T2 (verified: 0 conflicts, round 2).
// setprio(1) around the MFMA cluster — T5. XCD-bijective block swizzle — T1.
// Ledger: prologue issues stages(0)+stages(1) = 8 outstanding/wave.
//   top of tile t: outstanding = stages(t)[4] + stages(t+1)[4] -> vmcnt(4)
//   retires stages(t); per-wave wait then s_barrier makes all waves' data visible.
//   t=nt-2: 8 outstanding, vmcnt(4) ok; t=nt-1: 4 outstanding, vmcnt(0).
// MODE 0: in_proj — stream 0: la = -clip(softplus(acc+dt_bias[n]),0.001,2) (f32)
//                   stream 1: v raw (bf16);  stream 2: sigmoid -> gate (bf16)
// MODE 1: out_proj — out[off] = acc + resid[off]  (f32)
template<int MODE>
__global__ __launch_bounds__(512, 2) void k_gemm(const __hip_bfloat16* __restrict__ Abf,
                                              const __hip_bfloat16* __restrict__ Wbf,
                                              int K,
                                              float* __restrict__ o0,
                                              __hip_bfloat16* __restrict__ o1,
                                              __hip_bfloat16* __restrict__ o2,
                                              const float* __restrict__ dt_bias,
                                              const float* __restrict__ resid,
                                              float* __restrict__ outp)
{
    // [buf 0..2][A=0/B=1][256 rows x 32 cols bf16 = 16 KiB]
    __shared__ __attribute__((aligned(16))) char lds[3][2][16384];
    const __bf16* A = (const __bf16*)Abf;
    const __bf16* W = (const __bf16*)Wbf;
    const int tid  = threadIdx.x;
    const int wave = tid >> 6;
    const int lane = tid & 63;

    // T1: bijective XCD swizzle over linearized grid (nwg % 8 == 0 for all call sites)
    const int gx  = gridDim.x;
    int bid = blockIdx.y * gx + blockIdx.x;
    int cpx = (gx * gridDim.y) >> 3;
    int swzb = (bid & 7) * cpx + (bid >> 3);
    int bx = swzb % gx, by = swzb / gx;

    const size_t m0 = (size_t)bx * 256;
    const size_t n0 = (size_t)by * 256;
    const int wm = (wave & 1) * 128;      // 2 waves in M
    const int wn = (wave >> 1) * 64;      // 4 waves in N

    v4f acc[8][4] = {};

    // ---- read-side addressing (swizzled) ----
    const int fr = lane & 15;             // fragment row within 16
    const int qk = lane >> 4;             // k 16B-chunk 0..3
    const int colb = ((qk ^ ((fr >> 1) & 3)) << 4);   // swizzled byte col
    int rowA[8], rowB[4];
    #pragma unroll
    for (int i = 0; i < 8; ++i) rowA[i] = (wm + i*16 + fr) * 64;
    #pragma unroll
    for (int j = 0; j < 4; ++j) rowB[j] = (wn + j*16 + fr) * 64;

    // ---- stage-side addressing (linear LDS dest, pre-swizzled global src) ----
    const int rowi   = tid >> 2;          // 0..127 rows per 8 KiB issue
    const int col16s = tid & 3;           // 16B slot within 64 B row
    const int scol   = (col16s ^ ((rowi >> 1) & 3)) * 8;  // src element offset

    const int nt = K >> 5;                // BK=32

    // stage one 8 KiB half (128 rows) of A or B of tile t into buf[t%3]
    auto stage = [&](int t, int half, int isB) {
        char* dst = lds[t % 3][isB] + (half * 8192 + wave * 1024);
        int rfull = half * 128 + rowi;
        size_t grow = (isB ? n0 : m0) + (size_t)rfull;
        const __bf16* src = (isB ? W : A) + grow * (size_t)K + (t << 5) + scol;
        async_copy16((void*)dst, (const void*)src);
    };

    // prologue: stages(0) + stages(1) -> 8 outstanding per wave
    #pragma unroll
    for (int h = 0; h < 2; ++h) { stage(0, h, 0); stage(0, h, 1); }
    #pragma unroll
    for (int h = 0; h < 2; ++h) { stage(1, h, 0); stage(1, h, 1); }

    for (int t = 0; t < nt; ++t) {
        if (t + 1 < nt) { asm volatile("s_waitcnt vmcnt(4)" ::: "memory"); }
        else            { asm volatile("s_waitcnt vmcnt(0)" ::: "memory"); }
        __builtin_amdgcn_s_barrier();      // all waves' stages(t) now visible;
                                           // all waves' reads of buf (t-1)%3 consumed
        __builtin_amdgcn_sched_barrier(0);

        const char* Ab = lds[t % 3][0];
        const char* Bb = lds[t % 3][1];

        // stage tile t+2 into buf (t+2)%3 == (t-1)%3 — released by the barrier above
        if (t + 2 < nt) {
            stage(t + 2, 0, 0); stage(t + 2, 1, 0);
            stage(t + 2, 0, 1); stage(t + 2, 1, 1);
        }

        v8bf fa[8], fb[4];
        #pragma unroll
        for (int j = 0; j < 4; ++j) fb[j] = *(const v8bf*)(Bb + rowB[j] + colb);
        #pragma unroll
        for (int i = 0; i < 8; ++i) fa[i] = *(const v8bf*)(Ab + rowA[i] + colb);

        __builtin_amdgcn_s_setprio(1);
        #pragma unroll
        for (int i = 0; i < 8; ++i)
            #pragma unroll
            for (int j = 0; j < 4; ++j)
                acc[i][j] = __builtin_amdgcn_mfma_f32_16x16x32_bf16(fa[i], fb[j], acc[i][j], 0, 0, 0);
        __builtin_amdgcn_s_setprio(0);
    }

    // epilogue: C/D layout col=lane&15, row=(lane>>4)*4+r  (m89-verified)
    const int col = lane & 15;
    const int rb  = (lane >> 4) * 4;
    if (MODE == 0) {
        const int stream = by >> 3;                 // 2048/256 = 8 blocks/stream
        const size_t nb = n0 - (size_t)stream * D_;
        #pragma unroll
        for (int i = 0; i < 8; ++i)
            #pragma unroll
            for (int j = 0; j < 4; ++j) {
                size_t nIdx = nb + wn + j*16 + col;
                #pragma unroll
                for (int r = 0; r < 4; ++r) {
                    size_t m = m0 + wm + i*16 + rb + r;
                    size_t off = m * (size_t)D_ + nIdx;
                    float v = acc[i][j][r];
                    if (stream == 0) {
                        float xx = v + dt_bias[nIdx];
                        float e  = __expf(-fabsf(xx));
                        float sp = fmaxf(xx, 0.f) + __logf(1.f + e);
                        float dt = fminf(fmaxf(sp, 0.001f), 2.0f);
                        o0[off] = -dt;                                    // log_alpha
                    } else if (stream == 1) {
                        o1[off] = __float2bfloat16(v);                    // raw v
                    } else {
                        o2[off] = __float2bfloat16(1.f/(1.f+__expf(-v))); // gate
                    }
                }
            }
    } else {
        #pragma unroll
        for (int i = 0; i < 8; ++i)
            #pragma unroll
            for (int j = 0; j < 4; ++j)
                #pragma unroll
                for (int r = 0; r < 4; ++r) {
                    size_t m = m0 + wm + i*16 + rb + r;
                    size_t off = m * (size_t)D_ + n0 + wn + j*16 + col;
                    outp[off] = acc[i][j][r] + resid[off];
                }
    }
}

// ---------------- scan phase 1: RoPE*dt fused; per (b,chunk,d) -> bd, bo ----------------
__global__ __launch_bounds__(256) void k_scan1(const float* __restrict__ la,
                                               const __hip_bfloat16* __restrict__ v,
                                               float* __restrict__ bd, float* __restrict__ bo)
{
    int idx = blockIdx.x * 256 + threadIdx.x;   // B*NC*D = 65536
    int d = idx & (D_-1);
    int c = (idx >> 11) & (NC_-1);
    int b = idx >> 15;
    int i = d & 63;
    const bool firstHalf = (d & 64) == 0;
    float inv = __expf((float)i * (-9.210340371976184f / 64.f)); // 10000^(-i/64)
    int n0 = c * CHUNK_;
    // incremental rotation: (cs,sn) = (cos,sin)(n*inv), step by inv
    float cs = cosf((float)n0 * inv), sn = sinf((float)n0 * inv);
    float ca = cosf(inv), sa = sinf(inv);
    size_t row0 = (size_t)b * N_ + (size_t)c * CHUNK_;
    float S = 0.f, Lp = 0.f, out = 0.f;
    #pragma unroll 8
    for (int t = 0; t < CHUNK_; ++t) {
        size_t off = (row0 + t) * (size_t)D_ + d;
        float a  = la[off];
        float vo = __bfloat162float(v[off]);
        float vp = __bfloat162float(v[firstHalf ? off + 64 : off - 64]);
        float dt = -a;
        float vin = (firstHalf ? (vo*cs - vp*sn) : (vp*sn + vo*cs)) * dt;
        S += a;
        float L = fmaxf(S, -20.f);           // clip(cumsum,-20,0): upper never binds
        out = __expf(L - Lp) * out + vin;
        Lp = L;
        float csn = cs*ca - sn*sa;           // advance angle by inv
        sn = sn*ca + cs*sa;
        cs = csn;
    }
    bd[idx] = Lp;
    bo[idx] = out;
}

// ---------------- scan phase 2: cross-chunk combine -> carries ----------------
__global__ __launch_bounds__(256) void k_scan2(const float* __restrict__ bd,
                                               const float* __restrict__ bo,
                                               float* __restrict__ carries)
{
    int idx = blockIdx.x * 256 + threadIdx.x;   // B*D = 4096
    int d = idx & (D_-1);
    int b = idx >> 11;
    float bd0 = bd[(size_t)(b*NC_)*D_ + d];     // stab = cd[0] = bd[0] (>= -20)
    float cd = 0.f, acc = 0.f;
    #pragma unroll
    for (int c = 0; c < NC_; ++c) {
        size_t o = (size_t)(b*NC_ + c)*D_ + d;
        cd = fmaxf(cd + bd[o], -80.f);          // clip(cumsum(bd),-80,0)
        float ncd = fmaxf(cd - bd0, -20.f);     // clip(cd-stab,-20,0)
        carries[o] = acc * __expf(ncd);         // sum of seeds STRICTLY BEFORE c
        acc += bo[o] * __expf(-ncd);
    }
}

// ---------------- scan phase 3: recompute + carry; write state (bf16) ----------------
__global__ __launch_bounds__(256) void k_scan3(const float* __restrict__ la,
                                               const __hip_bfloat16* __restrict__ v,
                                               const float* __restrict__ carries,
                                               __hip_bfloat16* __restrict__ state)
{
    int idx = blockIdx.x * 256 + threadIdx.x;
    int d = idx & (D_-1);
    int c = (idx >> 11) & (NC_-1);
    int b = idx >> 15;
    int i = d & 63;
    const bool firstHalf = (d & 64) == 0;
    float inv = __expf((float)i * (-9.210340371976184f / 64.f));
    int n0 = c * CHUNK_;
    float cs = cosf((float)n0 * inv), sn = sinf((float)n0 * inv);
    float ca = cosf(inv), sa = sinf(inv);
    float carry = carries[idx];
    size_t row0 = (size_t)b * N_ + (size_t)c * CHUNK_;
    float S = 0.f, Lp = 0.f, out = 0.f;
    #pragma unroll 8
    for (int t = 0; t < CHUNK_; ++t) {
        size_t off = (row0 + t) * (size_t)D_ + d;
        float a  = la[off];
        float vo = __bfloat162float(v[off]);
        float vp = __bfloat162float(v[firstHalf ? off + 64 : off - 64]);
        float dt = -a;
        float vin = (firstHalf ? (vo*cs - vp*sn) : (vp*sn + vo*cs)) * dt;
        S += a;
        float L = fmaxf(S, -20.f);
        out = __expf(L - Lp) * out + vin;
        Lp = L;
        state[off] = __float2bfloat16(out + carry * __expf(L));
        float csn = cs*ca - sn*sa;
        sn = sn*ca + cs*sa;
        cs = csn;
    }
}

// ---------------- head_mix (generic 16x16) * gate -> y (bf16) ----------------
__global__ __launch_bounds__(256) void k_headmix_gate(const __hip_bfloat16* __restrict__ state,
                                                      const __hip_bfloat16* __restrict__ gate,
                                                      const float* __restrict__ hm,
                                                      __hip_bfloat16* __restrict__ y)
{
    __shared__ float lf[D_];
    __shared__ float lhm[H_*H_];
    const int row = blockIdx.x;
    const size_t base = (size_t)row * D_;
    u16x8 s8 = ((const u16x8*)(state + base))[threadIdx.x];
    #pragma unroll
    for (int j = 0; j < 8; ++j) lf[threadIdx.x*8 + j] = bf2f(s8[j]);
    if (threadIdx.x < H_*H_) lhm[threadIdx.x] = hm[threadIdx.x];
    __syncthreads();
    #pragma unroll
    for (int k = 0; k < 8; ++k) {
        int o = threadIdx.x + k*256;
        int m  = o >> 7;
        int dh = o & 127;
        float s = 0.f;
        #pragma unroll
        for (int h = 0; h < H_; ++h) s += lf[h*DH_ + dh] * lhm[h*H_ + m];
        float g = __bfloat162float(gate[base + o]);
        y[base + o] = __float2bfloat16(s * g);
    }
}

extern "C" void kernel_launch(void* const* d_in, const int* in_sizes, int n_in,
                              void* d_out, int out_size, void* d_ws, size_t ws_size,
                              hipStream_t stream)
{
    const float* x          = (const float*)d_in[0];
    const float* norm_scale = (const float*)d_in[1];
    const float* conv_w     = (const float*)d_in[2];
    const float* conv_b     = (const float*)d_in[3];
    const float* in_proj_w  = (const float*)d_in[4];
    const float* dt_bias    = (const float*)d_in[5];
    const float* head_mix   = (const float*)d_in[6];
    const float* out_proj_w = (const float*)d_in[7];
    float* out = (float*)d_out;

    // Workspace layout — total 176,947,200 B.
    char* ws = (char*)d_ws;
    float*          la   = (float*)ws;                               // 67,108,864 B (log_alpha, f32)
    __hip_bfloat16* xn   = (__hip_bfloat16*)(ws + 67108864);         // 33,554,432 B; reused for w1 after conv
    __hip_bfloat16* xc   = (__hip_bfloat16*)(ws + 100663296);        // 33,554,432 B; reused for y after GEMM1
    __hip_bfloat16* gate = (__hip_bfloat16*)(ws + 134217728);        // 33,554,432 B
    __hip_bfloat16* w2   = (__hip_bfloat16*)(ws + 167772160);        //  8,388,608 B
    float*          bd   = (float*)(ws + 176160768);                 //    262,144 B
    float*          bo   = (float*)(ws + 176422912);                 //    262,144 B
    float*          carr = (float*)(ws + 176685056);                 //    262,144 B
    __hip_bfloat16* w1   = xn;   // xn dead after conv
    __hip_bfloat16* y    = xc;   // xc dead after GEMM1
    // d_out as staged scratch: v (bf16, first half) and state (bf16, second half),
    // both fully dead before GEMM2 overwrites d_out with the final f32 output.
    __hip_bfloat16* v     = (__hip_bfloat16*)d_out;
    __hip_bfloat16* state = (__hip_bfloat16*)((char*)d_out + 33554432);

    k_rmsnorm<<<M_, 256, 0, stream>>>(x, norm_scale, xn);
    k_conv_silu<<<(M_*(size_t)D_)/8/256, 256, 0, stream>>>(xn, conv_w, conv_b, xc);
    k_cast_bf16<<<6144, 256, 0, stream>>>(in_proj_w, w1);
    k_cast_bf16<<<2048, 256, 0, stream>>>(out_proj_w, w2);
    k_gemm<0><<<dim3(M_/256, F3D/256), 512, 0, stream>>>(xc, w1, D_, la, v, gate, dt_bias, nullptr, nullptr);
    k_scan1<<<(B_*NC_*D_)/256, 256, 0, stream>>>(la, v, bd, bo);
    k_scan2<<<(B_*D_)/256, 256, 0, stream>>>(bd, bo, carr);
    k_scan3<<<(B_*NC_*D_)/256, 256, 0, stream>>>(la, v, carr, state);
    k_headmix_gate<<<M_, 256, 0, stream>>>(state, gate, head_mix, y);
    k_gemm<1><<<dim3(M_/256, D_/256), 512, 0, stream>>>(y, w2, D_, nullptr, nullptr, nullptr, nullptr, x, out);
}